// Round 6
// baseline (833.051 us; speedup 1.0000x reference)
//
#include <hip/hip_runtime.h>
#include <hip/hip_bf16.h>

// Problem: B=4096, F=512, C=64, MC=100, TRI=2080, N_all = 64+2080 = 2144
// Pipeline:
//  cvt:    x, [w_mu;w_sigma] -> bf16
//  gemm:   c_all = x @ W^T + bias. 128x128 tile, BK=64, LDS-staged via
//          global_load_lds(16B) with XOR-swizzled source; 17x32 grid, bijective
//          XCD remap. epilogue: cols<64 -> Mu f32; cols in [64,2144) -> Sg bf16
//          triangular (softplus+1e-6 on diagonal).
//  sample: out = sigmoid(mu + L @ eps) as O^T = (eps^T)(L^T), 16x16x32 MFMA.
//          1024 blocks x NB=4 consecutive b (ALL resident: 4 blocks/CU), 2-phase
//          single-buffered pipeline, LDS 37.9 KB:
//            phase1: pack ef(b)->frags | issue eps/Mu(b+1)->regs | gload16
//                    Sg(b+1)->raw | compute(b): MFMA+sigmoid -> flat Ost | bar
//            phase2: dump Ost->out[b] (contiguous, full-line exact writes) |
//                    expand raw->Lh(b+1) | bar
//          Single raw/Lh/Ost suffice: each producer/consumer pair is separated
//          by exactly one barrier. Round-4 lesson: no scattered direct stores.
//          Round-5 lesson: dbuf LDS costs a block/CU and pays nothing.

typedef short bf16x8 __attribute__((ext_vector_type(8)));   // 8 bf16 in 4 VGPRs
typedef float f32x4 __attribute__((ext_vector_type(4)));

__device__ __forceinline__ unsigned short f2bf(float f) {
    union { float f; unsigned u; } u; u.f = f;
    unsigned r = u.u + 0x7FFFu + ((u.u >> 16) & 1u);   // RNE
    return (unsigned short)(r >> 16);
}

__device__ __forceinline__ int swz(int r) { return (r ^ (r >> 3)) & 7; }

// tri index -> (i,j)  (gemm epilogue only; once per fragment column)
__device__ __forceinline__ void tri_ij(int t, int& i, int& j) {
    i = (int)((sqrtf((float)(8 * t + 1)) - 1.0f) * 0.5f);
    if ((i + 1) * (i + 2) / 2 <= t) ++i;
    if (i * (i + 1) / 2 > t) --i;
    j = t - ((i * (i + 1)) >> 1);
}

__device__ __forceinline__ void gload16(const void* g, void* l) {
    __builtin_amdgcn_global_load_lds(
        (const __attribute__((address_space(1))) void*)g,
        (__attribute__((address_space(3))) void*)l, 16, 0, 0);
}

// ---------------- kernel 1: f32 -> bf16 convert (x and concat(w_mu, w_sigma)) ----
__global__ __launch_bounds__(256) void cvt_kernel(
    const float* __restrict__ x, const float* __restrict__ wmu,
    const float* __restrict__ wsig,
    unsigned short* __restrict__ Xb, unsigned short* __restrict__ Wb) {
    const int NX = (4096 * 512) / 4;
    const int NW = (2144 * 512) / 4;
    const int NMU = (64 * 512) / 4;
    int tot = NX + NW;
    for (int i = blockIdx.x * blockDim.x + threadIdx.x; i < tot;
         i += gridDim.x * blockDim.x) {
        float4 v; unsigned short* dst;
        if (i < NX) {
            v = ((const float4*)x)[i];
            dst = Xb + (size_t)i * 4;
        } else {
            int j = i - NX;
            if (j < NMU) v = ((const float4*)wmu)[j];
            else         v = ((const float4*)wsig)[j - NMU];
            dst = Wb + (size_t)j * 4;
        }
        ushort4 o;
        o.x = f2bf(v.x); o.y = f2bf(v.y); o.z = f2bf(v.z); o.w = f2bf(v.w);
        *(ushort4*)dst = o;
    }
}

// ---------------- kernel 2: GEMM + triangular-Sg epilogue ------------------------
// 128x128 tile, BK=64, 4 waves (2x2), LDS A[128][64]+B[128][64] bf16 = 32 KB.
__global__ __launch_bounds__(256) void gemm_kernel(
    const unsigned short* __restrict__ Xb, const unsigned short* __restrict__ Wb,
    const float* __restrict__ bmu, const float* __restrict__ bsig,
    float* __restrict__ Mu, unsigned short* __restrict__ Sg) {
    __shared__ __align__(16) unsigned short smem[16384];   // A: [0,8192) B: [8192,16384)

    int flat = blockIdx.y * 17 + blockIdx.x;           // 0..543
    int virt = (flat & 7) * 68 + (flat >> 3);          // bijective XCD remap
    int vbx = virt % 17, vby = virt / 17;
    int r0 = vby * 128, c0 = vbx * 128;

    int tid = threadIdx.x;
    int w = tid >> 6, lane = tid & 63;
    int wr = w >> 1, wc = w & 1;
    int lr = lane & 15, kg = lane >> 4;

    int sr = tid >> 3;                 // 0..31 (row within 32-row stripe)
    int sc = tid & 7;                  // chunk 0..7
    int scx = sc ^ (sr & 7);           // inverse-swizzled source chunk
    const unsigned short* Ag = Xb + (size_t)(r0 + sr) * 512 + scx * 8;
    const unsigned short* Bg = Wb + (size_t)(c0 + sr) * 512 + scx * 8;
    unsigned short* As = smem + tid * 8;           // byte off = tid*16
    unsigned short* Bs = smem + 8192 + tid * 8;

    f32x4 acc[4][4];
    #pragma unroll
    for (int i = 0; i < 4; ++i)
        #pragma unroll
        for (int j = 0; j < 4; ++j) acc[i][j] = (f32x4){0.f, 0.f, 0.f, 0.f};

    for (int kt = 0; kt < 8; ++kt) {
        int k0 = kt * 64;
        #pragma unroll
        for (int i = 0; i < 4; ++i) {
            gload16(Ag + (size_t)i * 32 * 512 + k0, As + i * 2048);
            gload16(Bg + (size_t)i * 32 * 512 + k0, Bs + i * 2048);
        }
        __syncthreads();               // drains vmcnt -> staged tile visible
        #pragma unroll
        for (int h = 0; h < 2; ++h) {
            bf16x8 a[4], bv[4];
            #pragma unroll
            for (int i = 0; i < 4; ++i) {
                int row = wr * 64 + i * 16 + lr;
                int ch = ((h << 2) | kg) ^ (row & 7);
                a[i] = *(const bf16x8*)(smem + row * 64 + ch * 8);
            }
            #pragma unroll
            for (int j = 0; j < 4; ++j) {
                int row = wc * 64 + j * 16 + lr;
                int ch = ((h << 2) | kg) ^ (row & 7);
                bv[j] = *(const bf16x8*)(smem + 8192 + row * 64 + ch * 8);
            }
            #pragma unroll
            for (int i = 0; i < 4; ++i)
                #pragma unroll
                for (int j = 0; j < 4; ++j)
                    acc[i][j] = __builtin_amdgcn_mfma_f32_16x16x32_bf16(
                        a[i], bv[j], acc[i][j], 0, 0, 0);
        }
        __syncthreads();
    }

    int rbase = r0 + wr * 64 + (kg << 2);
    #pragma unroll
    for (int j = 0; j < 4; ++j) {
        int col = c0 + wc * 64 + j * 16 + lr;
        if (col < 64) {                        // mu head (wave-uniform branch)
            float bias = bmu[col];
            #pragma unroll
            for (int i = 0; i < 4; ++i)
                #pragma unroll
                for (int r = 0; r < 4; ++r)
                    Mu[(size_t)(rbase + i * 16 + r) * 64 + col] = acc[i][j][r] + bias;
        } else if (col < 2144) {               // sigma head -> triangular Sg
            int t = col - 64;
            float bias = bsig[t];
            int ti, tj; tri_ij(t, ti, tj);
            bool dg = (tj == ti);
            #pragma unroll
            for (int i = 0; i < 4; ++i) {
                #pragma unroll
                for (int r = 0; r < 4; ++r) {
                    float v = acc[i][j][r] + bias;
                    if (dg) v = (v > 15.f ? v : __logf(1.f + __expf(v))) + 1e-6f;
                    Sg[(size_t)(rbase + i * 16 + r) * 2080 + t] = f2bf(v);
                }
            }
        }
    }
}

// ---------------- kernel 3: out = sigmoid(mu + L @ eps) --------------------------
// 1024 blocks (4/CU, all resident), 8 waves, NB=4 consecutive b per block.
// 2-phase single-buffered pipeline; LDS 37.9 KB. See header comment.
__global__ __launch_bounds__(512, 8) void sample_kernel(
    const float* __restrict__ Mu, const unsigned short* __restrict__ Sg,
    const float* __restrict__ eps, float* __restrict__ out) {
    __shared__ __align__(16) unsigned short raw[2080];    // Sg row, 4.2 KB
    __shared__ __align__(16) unsigned short Lh[64][64];   // dense L, 8 KB
    __shared__ __align__(16) float Ost[6400];             // out[b] tile, 25.6 KB

    int flat = blockIdx.x;                      // 0..1023
    int virt = (flat & 7) * 128 + (flat >> 3);  // bijective XCD remap
    int b0 = virt << 2;

    int tid = threadIdx.x;
    int w = tid >> 6, lane = tid & 63;
    int lr = lane & 15, kg = lane >> 4;
    int m = (w << 4) + lr;
    int ml = (m < 100) ? m : 96;   // clamp: garbage rows never reach Ost
    int m0 = (w << 4) + (kg << 2);
    bool cw = (w < 7);
    bool st = cw && (m0 < 100);

    float ef[16], mun[4], muc[4];
    bf16x8 a0, a1;

    // ---- prologue: loads for b0 ----
    if (cw) {
        const float* er = eps + (size_t)b0 * 6400;
        #pragma unroll
        for (int s = 0; s < 8; ++s) {
            ef[s]     = er[(kg * 8 + s) * 100 + ml];
            ef[s + 8] = er[(32 + kg * 8 + s) * 100 + ml];
        }
        #pragma unroll
        for (int g = 0; g < 4; ++g)
            mun[g] = Mu[((size_t)b0 << 6) + g * 16 + lr];
    }
    if (tid < 260)
        gload16(Sg + (size_t)b0 * 2080 + tid * 8, &raw[tid * 8]);

    __syncthreads();                            // raw(b0) ready

    // expand raw -> Lh for b0
    #pragma unroll
    for (int kk = 0; kk < 4; ++kk) {
        int idx = tid + (kk << 9);              // 0..2047
        int i = idx >> 5;
        int j0 = (idx & 31) << 1;
        unsigned u = 0u;
        if (j0 <= i) {
            int t = ((i * (i + 1)) >> 1) + j0;
            u = raw[t];
            if (j0 + 1 <= i) u |= ((unsigned)raw[t + 1]) << 16;
        }
        *(unsigned*)&Lh[i][(((j0 >> 3) ^ swz(i)) << 3) | (j0 & 7)] = u;
    }

    __syncthreads();                            // Lh(b0) visible

    // ---- main loop: k = 0..3, b = b0+k ----
    #pragma unroll
    for (int k = 0; k < 4; ++k) {
        int b = b0 + k;

        // phase1: pack ef(b) -> frags; rotate mu
        if (cw) {
            #pragma unroll
            for (int s = 0; s < 4; ++s) {
                __hip_bfloat162 h0 = __float22bfloat162_rn(
                    make_float2(ef[2 * s], ef[2 * s + 1]));
                __hip_bfloat162 h1 = __float22bfloat162_rn(
                    make_float2(ef[8 + 2 * s], ef[8 + 2 * s + 1]));
                ((unsigned*)&a0)[s] = *(unsigned*)&h0;
                ((unsigned*)&a1)[s] = *(unsigned*)&h1;
            }
            #pragma unroll
            for (int g = 0; g < 4; ++g) muc[g] = mun[g];
        }

        // issue next-b loads (ef regs are free after pack; raw free after
        // last phase2's expand)
        if (k < 3) {
            if (cw) {
                const float* er = eps + (size_t)(b + 1) * 6400;
                #pragma unroll
                for (int s = 0; s < 8; ++s) {
                    ef[s]     = er[(kg * 8 + s) * 100 + ml];
                    ef[s + 8] = er[(32 + kg * 8 + s) * 100 + ml];
                }
                #pragma unroll
                for (int g = 0; g < 4; ++g)
                    mun[g] = Mu[((size_t)(b + 1) << 6) + g * 16 + lr];
            }
            if (tid < 260)
                gload16(Sg + (size_t)(b + 1) * 2080 + tid * 8, &raw[tid * 8]);
        }

        // compute(b): MFMA vs Lh, sigmoid -> flat Ost
        if (cw) {
            #pragma unroll
            for (int g = 0; g < 4; ++g) {
                int i = g * 16 + lr;
                int si = swz(i);
                bf16x8 L0 = *(const bf16x8*)&Lh[i][(kg ^ si) << 3];
                bf16x8 L1 = *(const bf16x8*)&Lh[i][((kg + 4) ^ si) << 3];
                f32x4 acc = {0.f, 0.f, 0.f, 0.f};
                acc = __builtin_amdgcn_mfma_f32_16x16x32_bf16(a0, L0, acc, 0, 0, 0);
                acc = __builtin_amdgcn_mfma_f32_16x16x32_bf16(a1, L1, acc, 0, 0, 0);
                if (st) {
                    float4 o;
                    #pragma unroll
                    for (int r = 0; r < 4; ++r) {
                        float z = muc[g] + acc[r];
                        ((float*)&o)[r] = __fdividef(1.f, 1.f + __expf(-z));
                    }
                    *(float4*)&Ost[i * 100 + m0] = o;   // 16B-aligned, 2-way banks
                }
            }
        }

        __syncthreads();   // Ost complete; raw(b+1) staged; Lh reads done

        // phase2: dump Ost -> out[b] (contiguous 1600 float4, full lines)
        {
            size_t ob = (size_t)b * 6400;
            #pragma unroll
            for (int kk = 0; kk < 4; ++kk) {
                int f = tid + (kk << 9);        // 0..2047
                if (f < 1600)
                    *(float4*)(out + ob + f * 4) = ((const float4*)Ost)[f];
            }
        }

        // expand raw -> Lh for b+1 (Lh reads finished at the barrier above)
        if (k < 3) {
            #pragma unroll
            for (int kk = 0; kk < 4; ++kk) {
                int idx = tid + (kk << 9);      // 0..2047
                int i = idx >> 5;
                int j0 = (idx & 31) << 1;
                unsigned u = 0u;
                if (j0 <= i) {
                    int t = ((i * (i + 1)) >> 1) + j0;
                    u = raw[t];
                    if (j0 + 1 <= i) u |= ((unsigned)raw[t + 1]) << 16;
                }
                *(unsigned*)&Lh[i][(((j0 >> 3) ^ swz(i)) << 3) | (j0 & 7)] = u;
            }
        }

        __syncthreads();   // Lh(b+1) visible; Ost consumed; raw reads done
    }
}

extern "C" void kernel_launch(void* const* d_in, const int* in_sizes, int n_in,
                              void* d_out, int out_size, void* d_ws, size_t ws_size,
                              hipStream_t stream) {
    const float* x    = (const float*)d_in[0];
    const float* eps  = (const float*)d_in[1];
    const float* wmu  = (const float*)d_in[2];
    const float* bmu  = (const float*)d_in[3];
    const float* wsig = (const float*)d_in[4];
    const float* bsig = (const float*)d_in[5];
    float* out = (float*)d_out;

    char* ws = (char*)d_ws;
    unsigned short* Xb = (unsigned short*)ws;                      // 4,194,304 B
    unsigned short* Wb = (unsigned short*)(ws + 4194304);          // 2,195,456 B
    float*          Mu = (float*)(ws + 4194304 + 2195456);         // 1,048,576 B
    unsigned short* Sg = (unsigned short*)(ws + 4194304 + 2195456 + 1048576); // 17,039,360 B

    cvt_kernel<<<2048, 256, 0, stream>>>(x, wmu, wsig, Xb, Wb);
    // N-tail note: bx=16 stages B rows 2144..2175 (reads past Wb into Mu region,
    // allocated workspace) — outputs there are write-guarded; safe.
    gemm_kernel<<<dim3(17, 32), 256, 0, stream>>>(Xb, Wb, bmu, bsig, Mu, Sg);
    sample_kernel<<<1024, 512, 0, stream>>>(Mu, Sg, eps, out);
}

// Round 7
// 77.989 us; speedup vs baseline: 10.6816x; 10.6816x over previous
//
#include <hip/hip_runtime.h>
#include <hip/hip_bf16.h>

// Problem: B=4096, F=512, C=64, MC=100, TRI=2080, N_all = 64+2080 = 2144
// Pipeline:
//  cvt:    x, [w_mu;w_sigma] -> bf16
//  gemm:   c_all = x @ W^T + bias. 128x128 tile, BK=64, LDS-staged via
//          global_load_lds(16B) with XOR-swizzled source; 17x32 grid, bijective
//          XCD remap. epilogue: cols<64 -> Mu f32; cols in [64,2144) -> Sg bf16
//          triangular (softplus+1e-6 on diagonal).
//  sample: out = sigmoid(mu + L @ eps) as O^T = (eps^T)(L^T), 16x16x32 MFMA.
//          1024 blocks x NB=4 consecutive b (4 blocks/CU), 2-phase single-
//          buffered pipeline, LDS 37.9 KB (see round-6 header).
//          ROUND-6 LESSON (the big one): __launch_bounds__ arg2 on this
//          toolchain acts like min-BLOCKS/CU: (512,8) capped VGPR at 32 ->
//          ef[16] pipeline spilled to scratch -> 2 GB write / 0.9 GB fetch
//          storm, 805 us. Fix: (512,4) -> VGPR cap 64 (4 blocks/CU is all
//          LDS permits anyway); drop mun/muc rotation (load muv in compute
//          phase, Mu is L2-hot) to shave 8 regs of live pressure.

typedef short bf16x8 __attribute__((ext_vector_type(8)));   // 8 bf16 in 4 VGPRs
typedef float f32x4 __attribute__((ext_vector_type(4)));

__device__ __forceinline__ unsigned short f2bf(float f) {
    union { float f; unsigned u; } u; u.f = f;
    unsigned r = u.u + 0x7FFFu + ((u.u >> 16) & 1u);   // RNE
    return (unsigned short)(r >> 16);
}

__device__ __forceinline__ int swz(int r) { return (r ^ (r >> 3)) & 7; }

// tri index -> (i,j)  (gemm epilogue only; once per fragment column)
__device__ __forceinline__ void tri_ij(int t, int& i, int& j) {
    i = (int)((sqrtf((float)(8 * t + 1)) - 1.0f) * 0.5f);
    if ((i + 1) * (i + 2) / 2 <= t) ++i;
    if (i * (i + 1) / 2 > t) --i;
    j = t - ((i * (i + 1)) >> 1);
}

__device__ __forceinline__ void gload16(const void* g, void* l) {
    __builtin_amdgcn_global_load_lds(
        (const __attribute__((address_space(1))) void*)g,
        (__attribute__((address_space(3))) void*)l, 16, 0, 0);
}

// ---------------- kernel 1: f32 -> bf16 convert (x and concat(w_mu, w_sigma)) ----
__global__ __launch_bounds__(256) void cvt_kernel(
    const float* __restrict__ x, const float* __restrict__ wmu,
    const float* __restrict__ wsig,
    unsigned short* __restrict__ Xb, unsigned short* __restrict__ Wb) {
    const int NX = (4096 * 512) / 4;
    const int NW = (2144 * 512) / 4;
    const int NMU = (64 * 512) / 4;
    int tot = NX + NW;
    for (int i = blockIdx.x * blockDim.x + threadIdx.x; i < tot;
         i += gridDim.x * blockDim.x) {
        float4 v; unsigned short* dst;
        if (i < NX) {
            v = ((const float4*)x)[i];
            dst = Xb + (size_t)i * 4;
        } else {
            int j = i - NX;
            if (j < NMU) v = ((const float4*)wmu)[j];
            else         v = ((const float4*)wsig)[j - NMU];
            dst = Wb + (size_t)j * 4;
        }
        ushort4 o;
        o.x = f2bf(v.x); o.y = f2bf(v.y); o.z = f2bf(v.z); o.w = f2bf(v.w);
        *(ushort4*)dst = o;
    }
}

// ---------------- kernel 2: GEMM + triangular-Sg epilogue ------------------------
// 128x128 tile, BK=64, 4 waves (2x2), LDS A[128][64]+B[128][64] bf16 = 32 KB.
__global__ __launch_bounds__(256) void gemm_kernel(
    const unsigned short* __restrict__ Xb, const unsigned short* __restrict__ Wb,
    const float* __restrict__ bmu, const float* __restrict__ bsig,
    float* __restrict__ Mu, unsigned short* __restrict__ Sg) {
    __shared__ __align__(16) unsigned short smem[16384];   // A: [0,8192) B: [8192,16384)

    int flat = blockIdx.y * 17 + blockIdx.x;           // 0..543
    int virt = (flat & 7) * 68 + (flat >> 3);          // bijective XCD remap
    int vbx = virt % 17, vby = virt / 17;
    int r0 = vby * 128, c0 = vbx * 128;

    int tid = threadIdx.x;
    int w = tid >> 6, lane = tid & 63;
    int wr = w >> 1, wc = w & 1;
    int lr = lane & 15, kg = lane >> 4;

    int sr = tid >> 3;                 // 0..31 (row within 32-row stripe)
    int sc = tid & 7;                  // chunk 0..7
    int scx = sc ^ (sr & 7);           // inverse-swizzled source chunk
    const unsigned short* Ag = Xb + (size_t)(r0 + sr) * 512 + scx * 8;
    const unsigned short* Bg = Wb + (size_t)(c0 + sr) * 512 + scx * 8;
    unsigned short* As = smem + tid * 8;           // byte off = tid*16
    unsigned short* Bs = smem + 8192 + tid * 8;

    f32x4 acc[4][4];
    #pragma unroll
    for (int i = 0; i < 4; ++i)
        #pragma unroll
        for (int j = 0; j < 4; ++j) acc[i][j] = (f32x4){0.f, 0.f, 0.f, 0.f};

    for (int kt = 0; kt < 8; ++kt) {
        int k0 = kt * 64;
        #pragma unroll
        for (int i = 0; i < 4; ++i) {
            gload16(Ag + (size_t)i * 32 * 512 + k0, As + i * 2048);
            gload16(Bg + (size_t)i * 32 * 512 + k0, Bs + i * 2048);
        }
        __syncthreads();               // drains vmcnt -> staged tile visible
        #pragma unroll
        for (int h = 0; h < 2; ++h) {
            bf16x8 a[4], bv[4];
            #pragma unroll
            for (int i = 0; i < 4; ++i) {
                int row = wr * 64 + i * 16 + lr;
                int ch = ((h << 2) | kg) ^ (row & 7);
                a[i] = *(const bf16x8*)(smem + row * 64 + ch * 8);
            }
            #pragma unroll
            for (int j = 0; j < 4; ++j) {
                int row = wc * 64 + j * 16 + lr;
                int ch = ((h << 2) | kg) ^ (row & 7);
                bv[j] = *(const bf16x8*)(smem + 8192 + row * 64 + ch * 8);
            }
            #pragma unroll
            for (int i = 0; i < 4; ++i)
                #pragma unroll
                for (int j = 0; j < 4; ++j)
                    acc[i][j] = __builtin_amdgcn_mfma_f32_16x16x32_bf16(
                        a[i], bv[j], acc[i][j], 0, 0, 0);
        }
        __syncthreads();
    }

    int rbase = r0 + wr * 64 + (kg << 2);
    #pragma unroll
    for (int j = 0; j < 4; ++j) {
        int col = c0 + wc * 64 + j * 16 + lr;
        if (col < 64) {                        // mu head (wave-uniform branch)
            float bias = bmu[col];
            #pragma unroll
            for (int i = 0; i < 4; ++i)
                #pragma unroll
                for (int r = 0; r < 4; ++r)
                    Mu[(size_t)(rbase + i * 16 + r) * 64 + col] = acc[i][j][r] + bias;
        } else if (col < 2144) {               // sigma head -> triangular Sg
            int t = col - 64;
            float bias = bsig[t];
            int ti, tj; tri_ij(t, ti, tj);
            bool dg = (tj == ti);
            #pragma unroll
            for (int i = 0; i < 4; ++i) {
                #pragma unroll
                for (int r = 0; r < 4; ++r) {
                    float v = acc[i][j][r] + bias;
                    if (dg) v = (v > 15.f ? v : __logf(1.f + __expf(v))) + 1e-6f;
                    Sg[(size_t)(rbase + i * 16 + r) * 2080 + t] = f2bf(v);
                }
            }
        }
    }
}

// ---------------- kernel 3: out = sigmoid(mu + L @ eps) --------------------------
// 1024 blocks (4/CU, all resident), 8 waves, NB=4 consecutive b per block.
// 2-phase single-buffered pipeline; LDS 37.9 KB.
// __launch_bounds__(512,4): VGPR cap 64 (NOT 8 -> cap 32 -> spill storm, r6).
__global__ __launch_bounds__(512, 4) void sample_kernel(
    const float* __restrict__ Mu, const unsigned short* __restrict__ Sg,
    const float* __restrict__ eps, float* __restrict__ out) {
    __shared__ __align__(16) unsigned short raw[2080];    // Sg row, 4.2 KB
    __shared__ __align__(16) unsigned short Lh[64][64];   // dense L, 8 KB
    __shared__ __align__(16) float Ost[6400];             // out[b] tile, 25.6 KB

    int flat = blockIdx.x;                      // 0..1023
    int virt = (flat & 7) * 128 + (flat >> 3);  // bijective XCD remap
    int b0 = virt << 2;

    int tid = threadIdx.x;
    int w = tid >> 6, lane = tid & 63;
    int lr = lane & 15, kg = lane >> 4;
    int m = (w << 4) + lr;
    int ml = (m < 100) ? m : 96;   // clamp: garbage rows never reach Ost
    int m0 = (w << 4) + (kg << 2);
    bool cw = (w < 7);
    bool st = cw && (m0 < 100);

    float ef[16];
    bf16x8 a0, a1;

    // ---- prologue: loads for b0 ----
    if (cw) {
        const float* er = eps + (size_t)b0 * 6400;
        #pragma unroll
        for (int s = 0; s < 8; ++s) {
            ef[s]     = er[(kg * 8 + s) * 100 + ml];
            ef[s + 8] = er[(32 + kg * 8 + s) * 100 + ml];
        }
    }
    if (tid < 260)
        gload16(Sg + (size_t)b0 * 2080 + tid * 8, &raw[tid * 8]);

    __syncthreads();                            // raw(b0) ready

    // expand raw -> Lh for b0
    #pragma unroll
    for (int kk = 0; kk < 4; ++kk) {
        int idx = tid + (kk << 9);              // 0..2047
        int i = idx >> 5;
        int j0 = (idx & 31) << 1;
        unsigned u = 0u;
        if (j0 <= i) {
            int t = ((i * (i + 1)) >> 1) + j0;
            u = raw[t];
            if (j0 + 1 <= i) u |= ((unsigned)raw[t + 1]) << 16;
        }
        *(unsigned*)&Lh[i][(((j0 >> 3) ^ swz(i)) << 3) | (j0 & 7)] = u;
    }

    __syncthreads();                            // Lh(b0) visible

    // ---- main loop: k = 0..3, b = b0+k ----
    #pragma unroll
    for (int k = 0; k < 4; ++k) {
        int b = b0 + k;

        // phase1: pack ef(b) -> frags
        if (cw) {
            #pragma unroll
            for (int s = 0; s < 4; ++s) {
                __hip_bfloat162 h0 = __float22bfloat162_rn(
                    make_float2(ef[2 * s], ef[2 * s + 1]));
                __hip_bfloat162 h1 = __float22bfloat162_rn(
                    make_float2(ef[8 + 2 * s], ef[8 + 2 * s + 1]));
                ((unsigned*)&a0)[s] = *(unsigned*)&h0;
                ((unsigned*)&a1)[s] = *(unsigned*)&h1;
            }
        }

        // issue next-b loads (ef regs free after pack; raw free after expand)
        if (k < 3) {
            if (cw) {
                const float* er = eps + (size_t)(b + 1) * 6400;
                #pragma unroll
                for (int s = 0; s < 8; ++s) {
                    ef[s]     = er[(kg * 8 + s) * 100 + ml];
                    ef[s + 8] = er[(32 + kg * 8 + s) * 100 + ml];
                }
            }
            if (tid < 260)
                gload16(Sg + (size_t)(b + 1) * 2080 + tid * 8, &raw[tid * 8]);
        }

        // compute(b): mu (L2-hot) + MFMA vs Lh, sigmoid -> flat Ost
        if (cw) {
            float muv[4];
            #pragma unroll
            for (int g = 0; g < 4; ++g)
                muv[g] = Mu[((size_t)b << 6) + g * 16 + lr];
            #pragma unroll
            for (int g = 0; g < 4; ++g) {
                int i = g * 16 + lr;
                int si = swz(i);
                bf16x8 L0 = *(const bf16x8*)&Lh[i][(kg ^ si) << 3];
                bf16x8 L1 = *(const bf16x8*)&Lh[i][((kg + 4) ^ si) << 3];
                f32x4 acc = {0.f, 0.f, 0.f, 0.f};
                acc = __builtin_amdgcn_mfma_f32_16x16x32_bf16(a0, L0, acc, 0, 0, 0);
                acc = __builtin_amdgcn_mfma_f32_16x16x32_bf16(a1, L1, acc, 0, 0, 0);
                if (st) {
                    float4 o;
                    #pragma unroll
                    for (int r = 0; r < 4; ++r) {
                        float z = muv[g] + acc[r];
                        ((float*)&o)[r] = __fdividef(1.f, 1.f + __expf(-z));
                    }
                    *(float4*)&Ost[i * 100 + m0] = o;   // 16B-aligned, 2-way banks
                }
            }
        }

        __syncthreads();   // Ost complete; raw(b+1) staged; Lh reads done

        // phase2: dump Ost -> out[b] (contiguous 1600 float4, full lines)
        {
            size_t ob = (size_t)b * 6400;
            #pragma unroll
            for (int kk = 0; kk < 4; ++kk) {
                int f = tid + (kk << 9);        // 0..2047
                if (f < 1600)
                    *(float4*)(out + ob + f * 4) = ((const float4*)Ost)[f];
            }
        }

        // expand raw -> Lh for b+1 (Lh reads finished at the barrier above)
        if (k < 3) {
            #pragma unroll
            for (int kk = 0; kk < 4; ++kk) {
                int idx = tid + (kk << 9);      // 0..2047
                int i = idx >> 5;
                int j0 = (idx & 31) << 1;
                unsigned u = 0u;
                if (j0 <= i) {
                    int t = ((i * (i + 1)) >> 1) + j0;
                    u = raw[t];
                    if (j0 + 1 <= i) u |= ((unsigned)raw[t + 1]) << 16;
                }
                *(unsigned*)&Lh[i][(((j0 >> 3) ^ swz(i)) << 3) | (j0 & 7)] = u;
            }
        }

        __syncthreads();   // Lh(b+1) visible; Ost consumed; raw reads done
    }
}

extern "C" void kernel_launch(void* const* d_in, const int* in_sizes, int n_in,
                              void* d_out, int out_size, void* d_ws, size_t ws_size,
                              hipStream_t stream) {
    const float* x    = (const float*)d_in[0];
    const float* eps  = (const float*)d_in[1];
    const float* wmu  = (const float*)d_in[2];
    const float* bmu  = (const float*)d_in[3];
    const float* wsig = (const float*)d_in[4];
    const float* bsig = (const float*)d_in[5];
    float* out = (float*)d_out;

    char* ws = (char*)d_ws;
    unsigned short* Xb = (unsigned short*)ws;                      // 4,194,304 B
    unsigned short* Wb = (unsigned short*)(ws + 4194304);          // 2,195,456 B
    float*          Mu = (float*)(ws + 4194304 + 2195456);         // 1,048,576 B
    unsigned short* Sg = (unsigned short*)(ws + 4194304 + 2195456 + 1048576); // 17,039,360 B

    cvt_kernel<<<2048, 256, 0, stream>>>(x, wmu, wsig, Xb, Wb);
    // N-tail note: bx=16 stages B rows 2144..2175 (reads past Wb into Mu region,
    // allocated workspace) — outputs there are write-guarded; safe.
    gemm_kernel<<<dim3(17, 32), 256, 0, stream>>>(Xb, Wb, bmu, bsig, Mu, Sg);
    sample_kernel<<<1024, 512, 0, stream>>>(Mu, Sg, eps, out);
}